// Round 1
// baseline (9120.932 us; speedup 1.0000x reference)
//
#include <hip/hip_runtime.h>
#include <hip/hip_bf16.h>

#define Hh 1024
#define INs 512
#define Bb 256
#define Tt 256
#define DT_ 0.1f
#define DELTA_T_ 1.0f
#define Z_MIN_ 0.001f
#define Z_MAX_ 0.1f
#define KW (Hh + INs)   // 1536, combined K-dim

typedef __attribute__((ext_vector_type(8))) short short8;
typedef __attribute__((ext_vector_type(4))) float f32x4;

__device__ __forceinline__ float sigmoidf_(float x) {
    return 1.0f / (1.0f + __expf(-x));
}

__device__ __forceinline__ unsigned short f2bf(float f) {
    union { float f; unsigned u; } v; v.f = f;
    unsigned r = v.u + 0x7FFFu + ((v.u >> 16) & 1u);  // RNE
    return (unsigned short)(r >> 16);
}

// ---- build W1=[K|p_z], W2=[w_r|p_r] as bf16 row-major 1024 x 1536 ----
__global__ __launch_bounds__(256) void build_weights(
    const float* __restrict__ Km, const float* __restrict__ p_z,
    const float* __restrict__ w_r, const float* __restrict__ p_r,
    unsigned short* __restrict__ W1, unsigned short* __restrict__ W2) {
    int idx = blockIdx.x * 256 + threadIdx.x;           // over 1024*1536
    int h = idx / KW, k = idx % KW;
    float a = (k < Hh) ? Km[h * Hh + k] : p_z[h * INs + (k - Hh)];
    float b = (k < Hh) ? w_r[h * Hh + k] : p_r[h * INs + (k - Hh)];
    W1[idx] = f2bf(a);
    W2[idx] = f2bf(b);
}

// ---- x (T, IN, B) fp32 -> xT (T, B, IN) bf16 ----
__global__ __launch_bounds__(256) void transpose_x(
    const float* __restrict__ x, unsigned short* __restrict__ xT) {
    __shared__ unsigned short tile[64][65];
    int t = blockIdx.z;
    int i0 = blockIdx.y * 64;   // input-dim tile
    int b0 = blockIdx.x * 64;   // batch tile
    int c = threadIdx.x & 63, rbase = threadIdx.x >> 6;
    const float* xp = x + (size_t)t * INs * Bb;
#pragma unroll
    for (int r = 0; r < 16; ++r) {
        int row = r * 4 + rbase;                         // i offset
        tile[row][c] = f2bf(xp[(size_t)(i0 + row) * Bb + (b0 + c)]);
    }
    __syncthreads();
    unsigned short* op = xT + (size_t)t * Bb * INs;
#pragma unroll
    for (int r = 0; r < 16; ++r) {
        int brow = r * 4 + rbase;                        // b offset
        op[(size_t)(b0 + brow) * INs + (i0 + c)] = tile[c][brow];
    }
}

// ---- gate-rate constants (H each) ----
__global__ __launch_bounds__(256) void precomp_gates(
    const float* __restrict__ c_x, const float* __restrict__ c_u,
    const float* __restrict__ c_U,
    float* __restrict__ zxv, float* __restrict__ zuv, float* __restrict__ Ucv) {
    int h = blockIdx.x * 256 + threadIdx.x;
    zxv[h] = Z_MIN_ + (Z_MAX_ - Z_MIN_) * sigmoidf_(c_x[h]);
    zuv[h] = Z_MIN_ + (Z_MAX_ - Z_MIN_) * sigmoidf_(c_u[h]);
    Ucv[h] = 0.9f * sigmoidf_(c_U[h]);
}

// ---- initial state: X_1, U_1, R_0, M_0, v0=0 ; layouts (B, H) ----
__global__ __launch_bounds__(256) void init_state(
    const float* __restrict__ zxv, const float* __restrict__ zuv,
    const float* __restrict__ Ucv,
    float* __restrict__ X, float* __restrict__ U, float* __restrict__ v0,
    unsigned short* __restrict__ R0, unsigned short* __restrict__ M0) {
    int idx = blockIdx.x * 256 + threadIdx.x;           // over B*H
    int h = idx & (Hh - 1);
    float zx = zxv[h], zu = zuv[h], Uc = Ucv[h];
    const float X0 = 1.0f, U0 = 0.9f, r = 0.5f;         // r_0 = sigmoid(0)
    float Xn = zx + (1.0f - zx) * X0 - DELTA_T_ * U0 * X0 * r;
    float Un = Uc * zu + (1.0f - zu) * U0 + DELTA_T_ * Uc * (1.0f - U0) * r;
    Un = fminf(fmaxf(Un, Uc), 1.0f);
    X[idx] = Xn; U[idx] = Un; v0[idx] = 0.0f;
    R0[idx] = f2bf(r);
    M0[idx] = f2bf(Un * Xn * r);
}

// ---- fused step: G1 = W1@[R;x], G2 = W2@[M;x]; epilogue: z, v_new, next R/M ----
__global__ __launch_bounds__(256) void step_kernel(
    const unsigned short* __restrict__ W1, const unsigned short* __restrict__ W2,
    const unsigned short* __restrict__ Rt, const unsigned short* __restrict__ Mt,
    const unsigned short* __restrict__ xTt,
    const float* __restrict__ vprev, float* __restrict__ vout,
    const float* __restrict__ g_z, const float* __restrict__ b_r,
    const float* __restrict__ zxv, const float* __restrict__ zuv,
    const float* __restrict__ Ucv,
    float* __restrict__ X, float* __restrict__ U,
    unsigned short* __restrict__ Rn, unsigned short* __restrict__ Mn) {

    const int tid = threadIdx.x;
    const int wave = tid >> 6, lane = tid & 63;
    const int m = lane & 15, q = lane >> 4;
    const int hbase = blockIdx.y * 64 + wave * 16;      // output-row tile (16 rows/wave)
    const int nbase = blockIdx.x * 32;                  // batch-col tile (32 cols/WG)
    const int aRow = hbase + m;

    f32x4 acc00 = {0,0,0,0}, acc01 = {0,0,0,0};         // G1, n-tiles 0/1
    f32x4 acc10 = {0,0,0,0}, acc11 = {0,0,0,0};         // G2, n-tiles 0/1

    const unsigned short* w1p = W1 + (size_t)aRow * KW;
    const unsigned short* w2p = W2 + (size_t)aRow * KW;
    const unsigned short* rp0 = Rt + (size_t)(nbase + m) * Hh;
    const unsigned short* rp1 = Rt + (size_t)(nbase + 16 + m) * Hh;
    const unsigned short* mp0 = Mt + (size_t)(nbase + m) * Hh;
    const unsigned short* mp1 = Mt + (size_t)(nbase + 16 + m) * Hh;

    // phase 1: recurrent K-range [0, 1024)
    for (int kk = 0; kk < Hh; kk += 32) {
        int kA = kk + q * 8;
        short8 a1 = *(const short8*)(w1p + kA);
        short8 a2 = *(const short8*)(w2p + kA);
        short8 bR0 = *(const short8*)(rp0 + kA);
        short8 bR1 = *(const short8*)(rp1 + kA);
        short8 bM0 = *(const short8*)(mp0 + kA);
        short8 bM1 = *(const short8*)(mp1 + kA);
        acc00 = __builtin_amdgcn_mfma_f32_16x16x32_bf16(a1, bR0, acc00, 0, 0, 0);
        acc01 = __builtin_amdgcn_mfma_f32_16x16x32_bf16(a1, bR1, acc01, 0, 0, 0);
        acc10 = __builtin_amdgcn_mfma_f32_16x16x32_bf16(a2, bM0, acc10, 0, 0, 0);
        acc11 = __builtin_amdgcn_mfma_f32_16x16x32_bf16(a2, bM1, acc11, 0, 0, 0);
    }
    // phase 2: input-projection K-range [1024, 1536) — shared x fragments
    const unsigned short* xp0 = xTt + (size_t)(nbase + m) * INs;
    const unsigned short* xp1 = xTt + (size_t)(nbase + 16 + m) * INs;
    for (int kk = 0; kk < INs; kk += 32) {
        int kA = kk + q * 8;
        short8 a1 = *(const short8*)(w1p + Hh + kA);
        short8 a2 = *(const short8*)(w2p + Hh + kA);
        short8 bx0 = *(const short8*)(xp0 + kA);
        short8 bx1 = *(const short8*)(xp1 + kA);
        acc00 = __builtin_amdgcn_mfma_f32_16x16x32_bf16(a1, bx0, acc00, 0, 0, 0);
        acc01 = __builtin_amdgcn_mfma_f32_16x16x32_bf16(a1, bx1, acc01, 0, 0, 0);
        acc10 = __builtin_amdgcn_mfma_f32_16x16x32_bf16(a2, bx0, acc10, 0, 0, 0);
        acc11 = __builtin_amdgcn_mfma_f32_16x16x32_bf16(a2, bx1, acc11, 0, 0, 0);
    }

    // epilogue: C/D frag lane holds col = lane&15, rows = hbase + q*4 + (0..3)
    const int h0 = hbase + q * 4;
    float zx[4], zu[4], Uc[4], gz[4], br[4];
#pragma unroll
    for (int e = 0; e < 4; ++e) {
        zx[e] = zxv[h0 + e]; zu[e] = zuv[h0 + e]; Uc[e] = Ucv[h0 + e];
        gz[e] = g_z[h0 + e]; br[e] = b_r[h0 + e];
    }
#pragma unroll
    for (int nt = 0; nt < 2; ++nt) {
        f32x4 g1 = nt ? acc01 : acc00;
        f32x4 g2 = nt ? acc11 : acc10;
        const int bcol = nbase + nt * 16 + m;
        const size_t base = (size_t)bcol * Hh + h0;
#pragma unroll
        for (int e = 0; e < 4; ++e) {
            float z = DT_ * sigmoidf_(g1[e] + gz[e]);
            float vold = vprev[base + e];
            float vnew = (1.0f - z) * vold + DT_ * (g2[e] + br[e]);
            vout[base + e] = vnew;
            // next step's elementwise update (r_{t+1}, X, U, M_{t+1})
            float r = sigmoidf_(vnew);
            float Xs = X[base + e], Us = U[base + e];
            float Xn2 = zx[e] + (1.0f - zx[e]) * Xs - DELTA_T_ * Us * Xs * r;
            float Un2 = Uc[e] * zu[e] + (1.0f - zu[e]) * Us
                      + DELTA_T_ * Uc[e] * (1.0f - Us) * r;
            Un2 = fminf(fmaxf(Un2, Uc[e]), 1.0f);
            X[base + e] = Xn2; U[base + e] = Un2;
            Rn[base + e] = f2bf(r);
            Mn[base + e] = f2bf(Un2 * Xn2 * r);
        }
    }
}

extern "C" void kernel_launch(void* const* d_in, const int* in_sizes, int n_in,
                              void* d_out, int out_size, void* d_ws, size_t ws_size,
                              hipStream_t stream) {
    const float* x   = (const float*)d_in[0];
    const float* c_x = (const float*)d_in[1];
    const float* c_u = (const float*)d_in[2];
    const float* c_U = (const float*)d_in[3];
    const float* w_r = (const float*)d_in[4];
    const float* p_r = (const float*)d_in[5];
    const float* b_r = (const float*)d_in[6];
    const float* g_z = (const float*)d_in[7];
    const float* Km  = (const float*)d_in[8];
    const float* p_z = (const float*)d_in[9];
    float* out = (float*)d_out;

    // workspace layout (all sizes multiple of 4 KB)
    char* w = (char*)d_ws;
    unsigned short* W1 = (unsigned short*)w;               w += (size_t)Hh * KW * 2;   // 3 MB
    unsigned short* W2 = (unsigned short*)w;               w += (size_t)Hh * KW * 2;   // 3 MB
    unsigned short* xT = (unsigned short*)w;               w += (size_t)Tt * Bb * INs * 2; // 64 MB
    unsigned short* Rb[2]; unsigned short* Mb[2];
    Rb[0] = (unsigned short*)w;                            w += (size_t)Bb * Hh * 2;
    Rb[1] = (unsigned short*)w;                            w += (size_t)Bb * Hh * 2;
    Mb[0] = (unsigned short*)w;                            w += (size_t)Bb * Hh * 2;
    Mb[1] = (unsigned short*)w;                            w += (size_t)Bb * Hh * 2;
    float* X   = (float*)w;                                w += (size_t)Bb * Hh * 4;
    float* U   = (float*)w;                                w += (size_t)Bb * Hh * 4;
    float* v0  = (float*)w;                                w += (size_t)Bb * Hh * 4;
    float* zxv = (float*)w;                                w += Hh * 4;
    float* zuv = (float*)w;                                w += Hh * 4;
    float* Ucv = (float*)w;                                w += Hh * 4;

    build_weights<<<(Hh * KW) / 256, 256, 0, stream>>>(Km, p_z, w_r, p_r, W1, W2);
    transpose_x<<<dim3(Bb / 64, INs / 64, Tt), 256, 0, stream>>>(x, xT);
    precomp_gates<<<Hh / 256, 256, 0, stream>>>(c_x, c_u, c_U, zxv, zuv, Ucv);
    init_state<<<(Bb * Hh) / 256, 256, 0, stream>>>(zxv, zuv, Ucv, X, U, v0,
                                                    Rb[0], Mb[0]);

    for (int t = 0; t < Tt; ++t) {
        const float* vprev = (t == 0) ? v0 : out + (size_t)(t - 1) * Bb * Hh;
        step_kernel<<<dim3(Bb / 32, Hh / 64), 256, 0, stream>>>(
            W1, W2, Rb[t & 1], Mb[t & 1], xT + (size_t)t * Bb * INs,
            vprev, out + (size_t)t * Bb * Hh,
            g_z, b_r, zxv, zuv, Ucv, X, U, Rb[(t + 1) & 1], Mb[(t + 1) & 1]);
    }
}

// Round 3
// 7714.845 us; speedup vs baseline: 1.1823x; 1.1823x over previous
//
#include <hip/hip_runtime.h>
#include <hip/hip_bf16.h>

#define Hh 1024
#define INs 512
#define Bb 256
#define Tt 256
#define DT_ 0.1f
#define Z_MIN_ 0.001f
#define Z_MAX_ 0.1f
#define KW (Hh + INs)   // 1536 combined K
#define NB 256          // persistent grid = 1 block per CU

typedef __attribute__((ext_vector_type(8))) short short8;
typedef __attribute__((ext_vector_type(4))) float f32x4;

__device__ __forceinline__ float sigmoidf_(float x) {
    return 1.0f / (1.0f + __expf(-x));
}

__device__ __forceinline__ unsigned short f2bf(float f) {
    union { float f; unsigned u; } v; v.f = f;
    unsigned r = v.u + 0x7FFFu + ((v.u >> 16) & 1u);  // RNE
    return (unsigned short)(r >> 16);
}

// ---- build W1=[K|p_z], W2=[w_r|p_r] as bf16 row-major 1024 x 1536 ----
__global__ __launch_bounds__(256) void build_weights(
    const float* __restrict__ Km, const float* __restrict__ p_z,
    const float* __restrict__ w_r, const float* __restrict__ p_r,
    unsigned short* __restrict__ W1, unsigned short* __restrict__ W2) {
    int idx = blockIdx.x * 256 + threadIdx.x;
    int h = idx / KW, k = idx % KW;
    float a = (k < Hh) ? Km[h * Hh + k] : p_z[h * INs + (k - Hh)];
    float b = (k < Hh) ? w_r[h * Hh + k] : p_r[h * INs + (k - Hh)];
    W1[idx] = f2bf(a);
    W2[idx] = f2bf(b);
}

// ---- x (T, IN, B) fp32 -> xT (T, B, IN) bf16 ----
__global__ __launch_bounds__(256) void transpose_x(
    const float* __restrict__ x, unsigned short* __restrict__ xT) {
    __shared__ unsigned short tile[64][65];
    int t = blockIdx.z;
    int i0 = blockIdx.y * 64;
    int b0 = blockIdx.x * 64;
    int c = threadIdx.x & 63, rbase = threadIdx.x >> 6;
    const float* xp = x + (size_t)t * INs * Bb;
#pragma unroll
    for (int r = 0; r < 16; ++r) {
        int row = r * 4 + rbase;
        tile[row][c] = f2bf(xp[(size_t)(i0 + row) * Bb + (b0 + c)]);
    }
    __syncthreads();
    unsigned short* op = xT + (size_t)t * Bb * INs;
#pragma unroll
    for (int r = 0; r < 16; ++r) {
        int brow = r * 4 + rbase;
        op[(size_t)(b0 + brow) * INs + (i0 + c)] = tile[c][brow];
    }
}

// ---- gate-rate constants (H each) ----
__global__ __launch_bounds__(256) void precomp_gates(
    const float* __restrict__ c_x, const float* __restrict__ c_u,
    const float* __restrict__ c_U,
    float* __restrict__ zxv, float* __restrict__ zuv, float* __restrict__ Ucv) {
    int h = blockIdx.x * 256 + threadIdx.x;
    zxv[h] = Z_MIN_ + (Z_MAX_ - Z_MIN_) * sigmoidf_(c_x[h]);
    zuv[h] = Z_MIN_ + (Z_MAX_ - Z_MIN_) * sigmoidf_(c_u[h]);
    Ucv[h] = 0.9f * sigmoidf_(c_U[h]);
}

// ---- initial R_0, M_0 (B,H) bf16 ; also zero the grid-barrier words ----
__global__ __launch_bounds__(256) void init_state(
    const float* __restrict__ zxv, const float* __restrict__ zuv,
    const float* __restrict__ Ucv,
    unsigned short* __restrict__ R0, unsigned short* __restrict__ M0,
    unsigned* __restrict__ bar) {
    int idx = blockIdx.x * 256 + threadIdx.x;           // over B*H
    if (idx < 2) bar[idx * 64] = 0;                     // cnt @0, gen @64
    int h = idx & (Hh - 1);
    float zx = zxv[h], zu = zuv[h], Uc = Ucv[h];
    const float r = 0.5f;                                // sigmoid(0)
    float Xn = zx + (1.0f - zx) - 0.45f;                 // X0=1,U0=0.9
    float Un = Uc * zu + (1.0f - zu) * 0.9f + Uc * 0.05f;
    Un = fminf(fmaxf(Un, Uc), 1.0f);
    R0[idx] = f2bf(r);
    M0[idx] = f2bf(Un * Xn * r);
}

// x-projection partial: chunks 16..23 of this wave's pinned weights
__device__ __forceinline__ void xproj(
    const unsigned short* xp0, const unsigned short* xp1,
    const short8* wf1, const short8* wf2,
    f32x4& a10, f32x4& a11, f32x4& a20, f32x4& a21) {
    f32x4 z = {0.0f, 0.0f, 0.0f, 0.0f};
    a10 = z; a11 = z; a20 = z; a21 = z;
#pragma unroll
    for (int c = 16; c < 24; ++c) {
        short8 bx0 = *(const short8*)(xp0 + (c - 16) * 32);
        short8 bx1 = *(const short8*)(xp1 + (c - 16) * 32);
        a10 = __builtin_amdgcn_mfma_f32_16x16x32_bf16(wf1[c], bx0, a10, 0, 0, 0);
        a11 = __builtin_amdgcn_mfma_f32_16x16x32_bf16(wf1[c], bx1, a11, 0, 0, 0);
        a20 = __builtin_amdgcn_mfma_f32_16x16x32_bf16(wf2[c], bx0, a20, 0, 0, 0);
        a21 = __builtin_amdgcn_mfma_f32_16x16x32_bf16(wf2[c], bx1, a21, 0, 0, 0);
    }
}

// ---- persistent kernel: all 256 timesteps, hand-rolled grid barrier ----
// 256 WGs x 256 thr; 1 block/CU forced by VGPR pressure (192 pinned weight
// VGPRs alone). WG tile 32 rows x 32 cols; waves rh (row half) x kh (K half).
// K split: kh owns recurrent [kh*512, kh*512+512) + x-proj [kh*256, kh*256+256).
__global__ __launch_bounds__(256, 1) void persist_kernel(
    const unsigned short* __restrict__ W1, const unsigned short* __restrict__ W2,
    const unsigned short* __restrict__ xT,
    unsigned short* __restrict__ Rb0, unsigned short* __restrict__ Rb1,
    unsigned short* __restrict__ Mb0, unsigned short* __restrict__ Mb1,
    float* __restrict__ out,
    const float* __restrict__ g_z, const float* __restrict__ b_r,
    const float* __restrict__ zxv, const float* __restrict__ zuv,
    const float* __restrict__ Ucv, unsigned* __restrict__ bar) {

    unsigned* cnt = bar;
    unsigned* gen = bar + 64;

    const int tid = threadIdx.x;
    const int wave = tid >> 6, lane = tid & 63;
    const int m = lane & 15, q = lane >> 4;
    const int rh = wave >> 1;          // 0..1: row half
    const int kh = wave & 1;           // 0..1: K half
    const int rowg = blockIdx.x >> 3;  // 32 row groups (32 rows each)
    const int colg = blockIdx.x & 7;   // 8 col groups (32 cols) — XCD-aligned

    const int arow = rowg * 32 + rh * 16 + m;
    const int krec = kh * 512;                 // recurrent K base
    const int kx = kh * 256;                   // x-proj K base (within IN)
    const int bcol0 = colg * 32 + m;
    const int bcol1 = colg * 32 + 16 + m;

    // ---- pin weights in registers: 16 recurrent + 8 x-proj chunks, x2 ----
    short8 wf1[24], wf2[24];
    {
        const unsigned short* w1r = W1 + (size_t)arow * KW + krec + q * 8;
        const unsigned short* w2r = W2 + (size_t)arow * KW + krec + q * 8;
#pragma unroll
        for (int c = 0; c < 16; ++c) {
            wf1[c] = *(const short8*)(w1r + c * 32);
            wf2[c] = *(const short8*)(w2r + c * 32);
        }
        const unsigned short* w1x = W1 + (size_t)arow * KW + Hh + kx + q * 8;
        const unsigned short* w2x = W2 + (size_t)arow * KW + Hh + kx + q * 8;
#pragma unroll
        for (int c = 16; c < 24; ++c) {
            wf1[c] = *(const short8*)(w1x + (c - 16) * 32);
            wf2[c] = *(const short8*)(w2x + (c - 16) * 32);
        }
    }

    // ---- epilogue constants + persistent per-lane state (kh==0 owns it) ----
    const int h04 = rowg * 32 + rh * 16 + q * 4;
    f32x4 zx4 = *(const f32x4*)(zxv + h04);
    f32x4 zu4 = *(const f32x4*)(zuv + h04);
    f32x4 Uc4 = *(const f32x4*)(Ucv + h04);
    f32x4 gz4 = *(const f32x4*)(g_z + h04);
    f32x4 br4 = *(const f32x4*)(b_r + h04);

    f32x4 vr[2], Xr[2], Ur[2];
#pragma unroll
    for (int nt = 0; nt < 2; ++nt)
#pragma unroll
        for (int e = 0; e < 4; ++e) {
            vr[nt][e] = 0.0f;
            float Xn = zx4[e] + (1.0f - zx4[e]) - 0.45f;
            float Un = Uc4[e] * zu4[e] + (1.0f - zu4[e]) * 0.9f + Uc4[e] * 0.05f;
            Un = fminf(fmaxf(Un, Uc4[e]), 1.0f);
            Xr[nt][e] = Xn; Ur[nt][e] = Un;
        }

    __shared__ f32x4 red[2][4][64];   // [rh][acc][lane]

    // pre-loop: x-projection partials for t=0
    f32x4 xa10, xa11, xa20, xa21;
    xproj(xT + (size_t)bcol0 * INs + kx + q * 8,
          xT + (size_t)bcol1 * INs + kx + q * 8, wf1, wf2,
          xa10, xa11, xa20, xa21);

    for (int t = 0; t < Tt; ++t) {
        const unsigned short* Rt = (t & 1) ? Rb1 : Rb0;
        const unsigned short* Mt = (t & 1) ? Mb1 : Mb0;
        unsigned short* Rn = (t & 1) ? Rb0 : Rb1;
        unsigned short* Mn = (t & 1) ? Mb0 : Mb1;

        f32x4 g10 = xa10, g11 = xa11, g20 = xa20, g21 = xa21;

        const unsigned short* rp0 = Rt + (size_t)bcol0 * Hh + krec + q * 8;
        const unsigned short* rp1 = Rt + (size_t)bcol1 * Hh + krec + q * 8;
        const unsigned short* mp0 = Mt + (size_t)bcol0 * Hh + krec + q * 8;
        const unsigned short* mp1 = Mt + (size_t)bcol1 * Hh + krec + q * 8;

#pragma unroll
        for (int c = 0; c < 16; ++c) {
            short8 bR0 = *(const short8*)(rp0 + c * 32);
            short8 bR1 = *(const short8*)(rp1 + c * 32);
            short8 bM0 = *(const short8*)(mp0 + c * 32);
            short8 bM1 = *(const short8*)(mp1 + c * 32);
            g10 = __builtin_amdgcn_mfma_f32_16x16x32_bf16(wf1[c], bR0, g10, 0, 0, 0);
            g11 = __builtin_amdgcn_mfma_f32_16x16x32_bf16(wf1[c], bR1, g11, 0, 0, 0);
            g20 = __builtin_amdgcn_mfma_f32_16x16x32_bf16(wf2[c], bM0, g20, 0, 0, 0);
            g21 = __builtin_amdgcn_mfma_f32_16x16x32_bf16(wf2[c], bM1, g21, 0, 0, 0);
        }

        if (kh == 1) {
            red[rh][0][lane] = g10;
            red[rh][1][lane] = g11;
            red[rh][2][lane] = g20;
            red[rh][3][lane] = g21;
        }
        __syncthreads();

        if (kh == 0) {
            g10 += red[rh][0][lane];
            g11 += red[rh][1][lane];
            g20 += red[rh][2][lane];
            g21 += red[rh][3][lane];

#pragma unroll
            for (int nt = 0; nt < 2; ++nt) {
                f32x4 g1 = nt ? g11 : g10;
                f32x4 g2 = nt ? g21 : g20;
                const int bcol = nt ? bcol1 : bcol0;
                const size_t base = (size_t)bcol * Hh + h04;
                f32x4 vv;
                ushort4 rq, mq;
#pragma unroll
                for (int e = 0; e < 4; ++e) {
                    float z = DT_ * sigmoidf_(g1[e] + gz4[e]);
                    float vnew = (1.0f - z) * vr[nt][e] + DT_ * (g2[e] + br4[e]);
                    vr[nt][e] = vnew;
                    vv[e] = vnew;
                    float r = sigmoidf_(vnew);
                    float Xs = Xr[nt][e], Us = Ur[nt][e];
                    float Xn = zx4[e] + (1.0f - zx4[e]) * Xs - Us * Xs * r;
                    float Un = Uc4[e] * zu4[e] + (1.0f - zu4[e]) * Us
                             + Uc4[e] * (1.0f - Us) * r;
                    Un = fminf(fmaxf(Un, Uc4[e]), 1.0f);
                    Xr[nt][e] = Xn; Ur[nt][e] = Un;
                    unsigned short rb = f2bf(r), mb = f2bf(Un * Xn * r);
                    if (e == 0) { rq.x = rb; mq.x = mb; }
                    else if (e == 1) { rq.y = rb; mq.y = mb; }
                    else if (e == 2) { rq.z = rb; mq.z = mb; }
                    else { rq.w = rb; mq.w = mb; }
                }
                *(f32x4*)(out + (size_t)t * Bb * Hh + base) = vv;
                *(ushort4*)(Rn + base) = rq;
                *(ushort4*)(Mn + base) = mq;
            }
        }
        __syncthreads();   // all epilogue stores issued (vmcnt drained at barrier)

        if (t + 1 < Tt) {
            // ---- arrive ----
            if (tid == 0) {
                __threadfence();   // agent-scope release (L2 writeback)
                unsigned a = __hip_atomic_fetch_add(cnt, 1u, __ATOMIC_ACQ_REL,
                                                    __HIP_MEMORY_SCOPE_AGENT);
                if (a == NB - 1u) {
                    __hip_atomic_store(cnt, 0u, __ATOMIC_RELAXED,
                                       __HIP_MEMORY_SCOPE_AGENT);
                    __hip_atomic_store(gen, (unsigned)(t + 1), __ATOMIC_RELEASE,
                                       __HIP_MEMORY_SCOPE_AGENT);
                }
            }
            // ---- overlap: x-projection for step t+1 (independent of barrier) ----
            const unsigned short* xn = xT + (size_t)(t + 1) * Bb * INs;
            xproj(xn + (size_t)bcol0 * INs + kx + q * 8,
                  xn + (size_t)bcol1 * INs + kx + q * 8, wf1, wf2,
                  xa10, xa11, xa20, xa21);
            // ---- wait ----
            if (tid == 0) {
                while (__hip_atomic_load(gen, __ATOMIC_ACQUIRE,
                                         __HIP_MEMORY_SCOPE_AGENT) < (unsigned)(t + 1))
                    __builtin_amdgcn_s_sleep(2);
                __threadfence();   // agent-scope acquire (cache invalidate)
            }
            __syncthreads();
        }
    }
}

extern "C" void kernel_launch(void* const* d_in, const int* in_sizes, int n_in,
                              void* d_out, int out_size, void* d_ws, size_t ws_size,
                              hipStream_t stream) {
    const float* x   = (const float*)d_in[0];
    const float* c_x = (const float*)d_in[1];
    const float* c_u = (const float*)d_in[2];
    const float* c_U = (const float*)d_in[3];
    const float* w_r = (const float*)d_in[4];
    const float* p_r = (const float*)d_in[5];
    const float* b_r = (const float*)d_in[6];
    const float* g_z = (const float*)d_in[7];
    const float* Km  = (const float*)d_in[8];
    const float* p_z = (const float*)d_in[9];
    float* out = (float*)d_out;

    char* w = (char*)d_ws;
    unsigned short* W1 = (unsigned short*)w;   w += (size_t)Hh * KW * 2;
    unsigned short* W2 = (unsigned short*)w;   w += (size_t)Hh * KW * 2;
    unsigned short* xT = (unsigned short*)w;   w += (size_t)Tt * Bb * INs * 2;
    unsigned short* Rb0 = (unsigned short*)w;  w += (size_t)Bb * Hh * 2;
    unsigned short* Rb1 = (unsigned short*)w;  w += (size_t)Bb * Hh * 2;
    unsigned short* Mb0 = (unsigned short*)w;  w += (size_t)Bb * Hh * 2;
    unsigned short* Mb1 = (unsigned short*)w;  w += (size_t)Bb * Hh * 2;
    float* zxv = (float*)w;                    w += 4096;
    float* zuv = (float*)w;                    w += 4096;
    float* Ucv = (float*)w;                    w += 4096;
    unsigned* bar = (unsigned*)w;              w += 4096;

    build_weights<<<(Hh * KW) / 256, 256, 0, stream>>>(Km, p_z, w_r, p_r, W1, W2);
    transpose_x<<<dim3(Bb / 64, INs / 64, Tt), 256, 0, stream>>>(x, xT);
    precomp_gates<<<Hh / 256, 256, 0, stream>>>(c_x, c_u, c_U, zxv, zuv, Ucv);
    init_state<<<(Bb * Hh) / 256, 256, 0, stream>>>(zxv, zuv, Ucv, Rb0, Mb0, bar);

    persist_kernel<<<NB, 256, 0, stream>>>(
        W1, W2, xT, Rb0, Rb1, Mb0, Mb1, out,
        g_z, b_r, zxv, zuv, Ucv, bar);
}